// Round 1
// baseline (284.030 us; speedup 1.0000x reference)
//
#include <hip/hip_runtime.h>

// Problem constants (from reference setup_inputs):
//   fm0: [16,3,80,80,85]  -> 26,112,000 floats, 19200 rows/batch, scale 80
//   fm1: [16,3,40,40,85]  ->  6,528,000 floats,  4800 rows/batch, scale 40
//   fm2: [16,3,20,20,85]  ->  1,632,000 floats,  1200 rows/batch, scale 20
//   out: [16, 25200, 85]  -> 34,272,000 floats
//
// Two-kernel structure:
//   K1 (stream): sigmoid EVERY channel, perfectly coalesced float4 in/out,
//       no per-channel classification, no row loads. 2 VMEM + ~20 VALU per
//       float4 (vs 6 VMEM + ~45 VALU before) -> should sit on the HBM
//       roofline (~274 MB at ~6 TB/s ~ 46 us).
//   K2 (fixup): one thread per row (403,200 rows); reads the 4 raw box
//       floats from the input and overwrites out[row][0..3] with the decoded
//       box. ~45 MB of scattered traffic, a few us. Runs after K1 on the
//       same stream, so the overwrite is ordered.
#define NROWS_OUT 25200
#define ROWS0 19200
#define ROWS1 4800
#define ROWS2 1200
#define NB 16
#define L0_FLOATS 26112000
#define L1_FLOATS 6528000
#define L2_FLOATS 1632000
#define TOTAL_FLOATS (L0_FLOATS + L1_FLOATS + L2_FLOATS)   // 34,272,000
#define TOTAL4   (TOTAL_FLOATS / 4)                        //  8,568,000
#define HALF4    (TOTAL4 / 2)                              //  4,284,000
#define NROWS_TOT (NB * NROWS_OUT)                         //    403,200

typedef float v4f __attribute__((ext_vector_type(4)));     // native vec for NT store

__device__ __forceinline__ float fast_sigmoid(float x) {
    // v_exp_f32 (+1 mul) + v_rcp_f32: ~4 VALU ops, rel err ~1e-6.
    float e = __expf(-x);
    return __builtin_amdgcn_rcpf(1.0f + e);
}

// ---------------- K1: pure sigmoid stream ----------------
// Alignment: f_local % 4 == 0, and the output shift per (b,level) is a
// multiple of 4 floats for all levels (DELTA*85 and OFF*85 are all %4==0),
// so load and store are 16B-aligned.
template <int ROWS, int OFF>
__device__ __forceinline__ void stream4(const float* __restrict__ in,
                                        float* __restrict__ out,
                                        int f_local) {
    constexpr int ROWS85 = ROWS * 85;
    const int b = f_local / ROWS85;            // magic-mul (const divisor)
    const v4f x = *(const v4f*)(in + f_local);
    v4f y;
    y.x = fast_sigmoid(x.x);
    y.y = fast_sigmoid(x.y);
    y.z = fast_sigmoid(x.z);
    y.w = fast_sigmoid(x.w);
    const int out_f = f_local + (b * (NROWS_OUT - ROWS) + OFF) * 85;
    __builtin_nontemporal_store(y, (v4f*)(out + out_f));
}

__device__ __forceinline__ void sdispatch(const float* __restrict__ fm0,
                                          const float* __restrict__ fm1,
                                          const float* __restrict__ fm2,
                                          float* __restrict__ out, int f) {
    if (f < L0_FLOATS) {
        stream4<ROWS0, 0>(fm0, out, f);
    } else if (f < L0_FLOATS + L1_FLOATS) {
        stream4<ROWS1, ROWS0>(fm1, out, f - L0_FLOATS);
    } else {
        stream4<ROWS2, ROWS0 + ROWS1>(fm2, out, f - (L0_FLOATS + L1_FLOATS));
    }
}

__global__ __launch_bounds__(256) void yolo_sigmoid_kernel(
    const float* __restrict__ fm0, const float* __restrict__ fm1,
    const float* __restrict__ fm2, float* __restrict__ out) {
    const int v = blockIdx.x * 256 + threadIdx.x;
    if (v >= HALF4) return;
    // Two independent float4s per thread (memory ILP); both halves stay
    // coalesced: consecutive lanes -> consecutive float4s.
    sdispatch(fm0, fm1, fm2, out, v * 4);
    sdispatch(fm0, fm1, fm2, out, (v + HALF4) * 4);
}

// ---------------- K2: box fix-up, one thread per row ----------------
// Faithful to the torch in-place sequence:
//   x1 = (b0 - b2/2)*W ; y1 = (b1 - b3/2)*H
//   x2 = (x1 + b2/2)*W ; y2 = (y1 + b3/2)*H     (W == H == SCALE)
template <int ROWS, int OFF, int SCALE>
__device__ __forceinline__ void fixrow(const float* __restrict__ in,
                                       float* __restrict__ out, int tloc) {
    const int b = tloc / ROWS;                 // magic-mul (const divisor)
    const int gin = tloc * 85;                 // row start in level buffer
    const float r0 = in[gin + 0];
    const float r1 = in[gin + 1];
    const float r2 = in[gin + 2];
    const float r3 = in[gin + 3];

    const float sc = (float)SCALE;
    const float h2 = 0.5f * r2, h3 = 0.5f * r3;
    const float q0 = (r0 - h2) * sc;           // x1
    const float q1 = (r1 - h3) * sc;           // y1
    const float q2 = (q0 + h2) * sc;           // x2
    const float q3 = (q1 + h3) * sc;           // y2

    const int gout = (tloc + b * (NROWS_OUT - ROWS) + OFF) * 85;
    out[gout + 0] = q0;
    out[gout + 1] = q1;
    out[gout + 2] = q2;
    out[gout + 3] = q3;
}

__global__ __launch_bounds__(256) void yolo_boxfix_kernel(
    const float* __restrict__ fm0, const float* __restrict__ fm1,
    const float* __restrict__ fm2, float* __restrict__ out) {
    const int t = blockIdx.x * 256 + threadIdx.x;
    if (t >= NROWS_TOT) return;
    if (t < NB * ROWS0) {
        fixrow<ROWS0, 0, 80>(fm0, out, t);
    } else if (t < NB * (ROWS0 + ROWS1)) {
        fixrow<ROWS1, ROWS0, 40>(fm1, out, t - NB * ROWS0);
    } else {
        fixrow<ROWS2, ROWS0 + ROWS1, 20>(fm2, out, t - NB * (ROWS0 + ROWS1));
    }
}

extern "C" void kernel_launch(void* const* d_in, const int* in_sizes, int n_in,
                              void* d_out, int out_size, void* d_ws, size_t ws_size,
                              hipStream_t stream) {
    const float* fm0 = (const float*)d_in[0];
    const float* fm1 = (const float*)d_in[1];
    const float* fm2 = (const float*)d_in[2];
    float* out = (float*)d_out;

    const int blocks1 = (HALF4 + 255) / 256;        // 16,735
    hipLaunchKernelGGL(yolo_sigmoid_kernel, dim3(blocks1), dim3(256), 0, stream,
                       fm0, fm1, fm2, out);

    const int blocks2 = (NROWS_TOT + 255) / 256;    // 1,575
    hipLaunchKernelGGL(yolo_boxfix_kernel, dim3(blocks2), dim3(256), 0, stream,
                       fm0, fm1, fm2, out);
}

// Round 2
// 247.066 us; speedup vs baseline: 1.1496x; 1.1496x over previous
//
#include <hip/hip_runtime.h>

// Problem constants (from reference setup_inputs):
//   fm0: [16,3,80,80,85]  -> 26,112,000 floats, 19200 rows/batch, scale 80
//   fm1: [16,3,40,40,85]  ->  6,528,000 floats,  4800 rows/batch, scale 40
//   fm2: [16,3,20,20,85]  ->  1,632,000 floats,  1200 rows/batch, scale 20
//   out: [16, 25200, 85]  -> 34,272,000 floats
//
// Single merged kernel (round-0 math, verified correct), restructured as a
// memory-bound streaming kernel per Guideline 11:
//   - 2048 blocks x 256 threads, grid-stride (long-lived waves, steady-state
//     pipelining like the 6.29 TB/s float4-copy reference shape)
//   - 4 independent quarter-streams per loop iteration (4 loads in flight);
//     quarters 0-2 are statically level-0 (3*Q4 < L0 float4s) -> no branch
//   - PLAIN stores (not nontemporal): the 137 MB output fits in the 256 MB
//     L3, so plain stores can be absorbed/deferred by the cache hierarchy;
//     NT forced synchronous HBM writes.
#define NROWS_OUT 25200
#define L0_FLOATS 26112000
#define L1_FLOATS 6528000
#define L2_FLOATS 1632000
#define TOTAL_FLOATS (L0_FLOATS + L1_FLOATS + L2_FLOATS)   // 34,272,000
#define TOTAL4   (TOTAL_FLOATS / 4)                        //  8,568,000
#define Q4       (TOTAL4 / 4)                              //  2,142,000
#define NBLOCKS  2048
#define NTHREADS (NBLOCKS * 256)                           //    524,288
#define NITER    ((Q4 + NTHREADS - 1) / NTHREADS)          //          5

typedef float v4f __attribute__((ext_vector_type(4)));

__device__ __forceinline__ float fast_sigmoid(float x) {
    // v_exp_f32 (+1 mul) + v_rcp_f32: ~4 VALU ops, rel err ~1e-6.
    float e = __expf(-x);
    return __builtin_amdgcn_rcpf(1.0f + e);
}

// Branchless processing of one aligned float4 from a level's flat buffer.
// ROWS/OFF/SCALE are per-level compile-time constants.
//
// Alignment: f_local % 4 == 0, and the output shift per (b,level) is a
// multiple of 4 floats for all levels, so load and store are 16B-aligned.
//
// Box handling: channels 0..3 of at most ONE row intersect this float4
// (c0<=3 XOR c0>=82). Its row start g is computed unconditionally (dummy =
// own address when absent) and the 4 row floats are loaded up-front; they
// hit L1 (same lines as the main stream).
template <int ROWS, int OFF, int SCALE>
__device__ __forceinline__ void process4(const float* __restrict__ in,
                                         float* __restrict__ out,
                                         int f_local) {
    constexpr int ROWS85 = ROWS * 85;
    const int b   = f_local / ROWS85;          // magic-mul (const divisor)
    const int rem = f_local - b * ROWS85;      // j*85 + c within batch
    const int c0  = rem % 85;                  // channel of first element

    // Box row start (flat index in this level's buffer); dummy when no box.
    int g = f_local;
    if (c0 <= 3)  g = f_local - c0;            // row began at/just before us
    if (c0 >= 82) g = f_local + (85 - c0);     // next row begins inside us
    // (c0<=3 and c0>=82 are mutually exclusive; g stays in-bounds: buffers
    //  are whole rows, and c0>=82 implies the next row exists in full.)

    const v4f x = *(const v4f*)(in + f_local);
    const float r0 = in[g + 0];
    const float r1 = in[g + 1];
    const float r2 = in[g + 2];
    const float r3 = in[g + 3];

    const float sc = (float)SCALE;
    const float h2 = 0.5f * r2, h3 = 0.5f * r3;
    const float q0 = (r0 - h2) * sc;           // x1
    const float q1 = (r1 - h3) * sc;           // y1
    const float q2 = (q0 + h2) * sc;           // x2
    const float q3 = (q1 + h3) * sc;           // y2

    float xv[4] = {x.x, x.y, x.z, x.w};
    float y[4];
#pragma unroll
    for (int k = 0; k < 4; ++k) {
        int c = c0 + k;
        if (c >= 85) c -= 85;                  // at most one row wrap
        const float s = fast_sigmoid(xv[k]);
        const float q = (c == 0) ? q0 : ((c == 1) ? q1 : ((c == 2) ? q2 : q3));
        y[k] = (c < 4) ? q : s;                // v_cndmask chain, no branch
    }

    const int out_f = (b * NROWS_OUT + OFF) * 85 + rem;
    v4f yo; yo.x = y[0]; yo.y = y[1]; yo.z = y[2]; yo.w = y[3];
    *(v4f*)(out + out_f) = yo;                 // plain store: L2/L3-visible
}

__device__ __forceinline__ void dispatch4(const float* __restrict__ fm0,
                                          const float* __restrict__ fm1,
                                          const float* __restrict__ fm2,
                                          float* __restrict__ out, int f) {
    if (f < L0_FLOATS) {
        process4<19200, 0, 80>(fm0, out, f);
    } else if (f < L0_FLOATS + L1_FLOATS) {
        process4<4800, 19200, 40>(fm1, out, f - L0_FLOATS);
    } else {
        process4<1200, 24000, 20>(fm2, out, f - (L0_FLOATS + L1_FLOATS));
    }
}

__global__ __launch_bounds__(256) void yolo_decode_kernel(
    const float* __restrict__ fm0, const float* __restrict__ fm1,
    const float* __restrict__ fm2, float* __restrict__ out) {
    const int t = blockIdx.x * 256 + threadIdx.x;
    // Grid-stride over the first quarter; each iteration also handles the
    // mirrored float4 in quarters 2,3,4 -> 4 independent coalesced streams.
    // 3*Q4 = 6,426,000 < L0 float4s (6,528,000), so quarters 0-2 are
    // statically level-0: no dispatch branch, loads freely hoistable.
    for (int j = 0; j < NITER; ++j) {
        const int v = t + j * NTHREADS;
        if (v < Q4) {
            process4<19200, 0, 80>(fm0, out, v * 4);
            process4<19200, 0, 80>(fm0, out, (v + Q4) * 4);
            process4<19200, 0, 80>(fm0, out, (v + 2 * Q4) * 4);
            dispatch4(fm0, fm1, fm2, out, (v + 3 * Q4) * 4);
        }
    }
}

extern "C" void kernel_launch(void* const* d_in, const int* in_sizes, int n_in,
                              void* d_out, int out_size, void* d_ws, size_t ws_size,
                              hipStream_t stream) {
    const float* fm0 = (const float*)d_in[0];
    const float* fm1 = (const float*)d_in[1];
    const float* fm2 = (const float*)d_in[2];
    float* out = (float*)d_out;

    hipLaunchKernelGGL(yolo_decode_kernel, dim3(NBLOCKS), dim3(256), 0, stream,
                       fm0, fm1, fm2, out);
}

// Round 3
// 236.518 us; speedup vs baseline: 1.2009x; 1.0446x over previous
//
#include <hip/hip_runtime.h>

// Problem constants (from reference setup_inputs):
//   fm0: [16,3,80,80,85]  -> 26,112,000 floats, 19200 rows/batch, scale 80
//   fm1: [16,3,40,40,85]  ->  6,528,000 floats,  4800 rows/batch, scale 40
//   fm2: [16,3,20,20,85]  ->  1,632,000 floats,  1200 rows/batch, scale 20
//   out: [16, 25200, 85]  -> 34,272,000 floats
//
// Bottleneck model (round-2 counters): VMEM *instruction issue* ~1/cycle/CU,
// not bytes (kernel ran at 2.4 TB/s HBM, VALUBusy 24.6%, occupancy 75%).
// This version cuts VMEM instrs per float4 from 6 to 3:
//   - the 4 scalar row loads are replaced by ONE aligned neighbor dwordx4:
//     the row floats r0..r3 always lie in the lane's own float4 plus at most
//     one adjacent aligned float4 (prev when c0 in 1..3, next when c0>=82,
//     none when c0==0 or 4..81). A funnel select (~18 VALU, plenty of VALU
//     headroom) reconstructs r0..r3.
// Structure otherwise identical to the round-0 best (72 us inferred):
// one-shot grid, two half-streams per thread, nontemporal store.
#define NROWS_OUT 25200
#define L0_FLOATS 26112000
#define L1_FLOATS 6528000
#define L2_FLOATS 1632000
#define TOTAL_FLOATS (L0_FLOATS + L1_FLOATS + L2_FLOATS)   // 34,272,000
#define TOTAL4   (TOTAL_FLOATS / 4)                        //  8,568,000
#define HALF4    (TOTAL4 / 2)                              //  4,284,000

typedef float v4f __attribute__((ext_vector_type(4)));

__device__ __forceinline__ float fast_sigmoid(float x) {
    // v_exp_f32 (+1 mul) + v_rcp_f32: ~4 VALU ops, rel err ~1e-6.
    float e = __expf(-x);
    return __builtin_amdgcn_rcpf(1.0f + e);
}

// One aligned float4 of a level's flat buffer. ROWS/OFF/SCALE compile-time.
//
// Alignment: f_local % 4 == 0; output shift per (b,level) is a multiple of
// 4 floats for all levels, so load and store are 16B-aligned.
//
// Row-float reconstruction (replaces 4 scalar loads with 1 vec load):
//   g = row start intersecting this float4 (g = f-c0 if c0<=3, f+(85-c0) if
//   c0>=82). Needed floats beyond our own x are all inside ONE aligned
//   neighbor float4: prev (f-4) for c0 in 1..3, next (f+4) for c0 in 82..84.
//   Window w[0..6] = prevNeeded ? [n|x] : [x|n]; r_k = w[idx+k] where
//   idx = prevNeeded ? 4-c0 : (nextNeeded ? 85-c0 : 0), idx in 0..3.
//   In-bounds: c0 in 1..3 => f>=4; c0>=82 => next row exists in full (last
//   float4 of a level has c0 = (ROWS85-4) % 85 = 81, never >=82).
template <int ROWS, int OFF, int SCALE>
__device__ __forceinline__ void process4(const float* __restrict__ in,
                                         float* __restrict__ out,
                                         int f_local) {
    constexpr int ROWS85 = ROWS * 85;
    const int b   = f_local / ROWS85;          // magic-mul (const divisor)
    const int rem = f_local - b * ROWS85;      // j*85 + c within batch
    const int c0  = rem % 85;                  // channel of first element

    const bool prevNeeded = (c0 >= 1) && (c0 <= 3);
    const bool nextNeeded = (c0 >= 82);
    int nb = f_local;                          // dummy: own address
    if (prevNeeded) nb = f_local - 4;
    if (nextNeeded) nb = f_local + 4;

    const v4f x = *(const v4f*)(in + f_local);
    const v4f n = *(const v4f*)(in + nb);

    // 7-wide window, static names only (rule #20: no runtime-indexed arrays)
    const float w0 = prevNeeded ? n.x : x.x;
    const float w1 = prevNeeded ? n.y : x.y;
    const float w2 = prevNeeded ? n.z : x.z;
    const float w3 = prevNeeded ? n.w : x.w;
    const float w4 = prevNeeded ? x.x : n.x;
    const float w5 = prevNeeded ? x.y : n.y;
    const float w6 = prevNeeded ? x.z : n.z;
    const int idx = prevNeeded ? (4 - c0) : (nextNeeded ? (85 - c0) : 0);
    const bool i1 = (idx & 1) != 0;
    const bool i2 = (idx & 2) != 0;
    // funnel shift by idx (0..3): shift 2, then shift 1
    const float a0 = i2 ? w2 : w0;
    const float a1 = i2 ? w3 : w1;
    const float a2 = i2 ? w4 : w2;
    const float a3 = i2 ? w5 : w3;
    const float a4 = i2 ? w6 : w4;
    const float r0 = i1 ? a1 : a0;
    const float r1 = i1 ? a2 : a1;
    const float r2 = i1 ? a3 : a2;
    const float r3 = i1 ? a4 : a3;

    // Faithful to the torch in-place sequence (W == H == SCALE):
    const float sc = (float)SCALE;
    const float h2 = 0.5f * r2, h3 = 0.5f * r3;
    const float q0 = (r0 - h2) * sc;           // x1
    const float q1 = (r1 - h3) * sc;           // y1
    const float q2 = (q0 + h2) * sc;           // x2
    const float q3 = (q1 + h3) * sc;           // y2

    float xv[4] = {x.x, x.y, x.z, x.w};
    float y[4];
#pragma unroll
    for (int k = 0; k < 4; ++k) {
        int c = c0 + k;
        if (c >= 85) c -= 85;                  // at most one row wrap
        const float s = fast_sigmoid(xv[k]);
        const float q = (c == 0) ? q0 : ((c == 1) ? q1 : ((c == 2) ? q2 : q3));
        y[k] = (c < 4) ? q : s;                // v_cndmask chain, no branch
    }

    const int out_f = (b * NROWS_OUT + OFF) * 85 + rem;
    v4f yo; yo.x = y[0]; yo.y = y[1]; yo.z = y[2]; yo.w = y[3];
    __builtin_nontemporal_store(yo, (v4f*)(out + out_f));
}

__device__ __forceinline__ void dispatch4(const float* __restrict__ fm0,
                                          const float* __restrict__ fm1,
                                          const float* __restrict__ fm2,
                                          float* __restrict__ out, int f) {
    if (f < L0_FLOATS) {
        process4<19200, 0, 80>(fm0, out, f);
    } else if (f < L0_FLOATS + L1_FLOATS) {
        process4<4800, 19200, 40>(fm1, out, f - L0_FLOATS);
    } else {
        process4<1200, 24000, 20>(fm2, out, f - (L0_FLOATS + L1_FLOATS));
    }
}

__global__ __launch_bounds__(256) void yolo_decode_kernel(
    const float* __restrict__ fm0, const float* __restrict__ fm1,
    const float* __restrict__ fm2, float* __restrict__ out) {
    const int v = blockIdx.x * 256 + threadIdx.x;
    if (v >= HALF4) return;
    // Two independent float4s per thread (memory ILP); both halves stay
    // coalesced: consecutive lanes -> consecutive float4s.
    dispatch4(fm0, fm1, fm2, out, v * 4);
    dispatch4(fm0, fm1, fm2, out, (v + HALF4) * 4);
}

extern "C" void kernel_launch(void* const* d_in, const int* in_sizes, int n_in,
                              void* d_out, int out_size, void* d_ws, size_t ws_size,
                              hipStream_t stream) {
    const float* fm0 = (const float*)d_in[0];
    const float* fm1 = (const float*)d_in[1];
    const float* fm2 = (const float*)d_in[2];
    float* out = (float*)d_out;

    const int blocks = (HALF4 + 255) / 256;  // 16,735
    hipLaunchKernelGGL(yolo_decode_kernel, dim3(blocks), dim3(256), 0, stream,
                       fm0, fm1, fm2, out);
}